// Round 22
// baseline (3185.674 us; speedup 1.0000x reference)
//
#include <hip/hip_runtime.h>
#include <math.h>

// Problem constants (fixed by the reference)
#define BQ 32
#define DQ 512
#define TQ 2048
#define VQ 1024
#define QQ 6
#define NQ (BQ * TQ)                 // 65536 rows
#define NDQ ((size_t)NQ * DQ)        // 33,554,432 elements

#define EPS_TIE 1.5f    // bf16-est near-tie margin (>>8 sigma of bf16 GEMM noise)

typedef __attribute__((ext_vector_type(8))) short short8;   // 8 bf16 (4 VGPR)
typedef __attribute__((ext_vector_type(4))) float f32x4;    // MFMA acc

union FragU { ushort4 h[2]; short8 v; };

// fp32 -> bf16 RNE (bit trick; exactness of this rounding is NOT relied upon)
__device__ __forceinline__ ushort f2bf(float f) {
    unsigned u = __float_as_uint(f);
    return (ushort)((u + 0x7FFFu + ((u >> 16) & 1u)) >> 16);
}

// B-tile LDS swizzle (layout only; values untouched) — fallback path
__device__ __forceinline__ int bswz(int kk, int vv) {
    return vv ^ ((((kk & 7) ^ ((vv >> 5) & 7))) << 2);
}

// ---------------------------------------------------------------------------
// numpy-pairwise fp32 ||c||^2 (proven bit-exact)
__global__ void cnorm32_kernel(const float* __restrict__ cb, float* __restrict__ cn) {
    #pragma clang fp contract(off)
    int gw = (blockIdx.x * blockDim.x + threadIdx.x) >> 5;
    int l  = threadIdx.x & 31;
    if (gw >= QQ * VQ) return;
    const float* row = cb + (size_t)gw * DQ;
    const int c = l >> 3, j = l & 7;
    float acc = 0.f;
    #pragma unroll
    for (int m = 0; m < 16; m++) {
        float v = row[c * 128 + m * 8 + j];
        float a = v * v;
        acc = acc + a;
    }
    float s = acc + __shfl_xor(acc, 1, 64);
    s = s + __shfl_xor(s, 2, 64);
    s = s + __shfl_xor(s, 4, 64);
    float t = s + __shfl_xor(s, 8, 64);
    t = t + __shfl_xor(t, 16, 64);
    if (l == 0) cn[gw] = t;
}

// ---------------------------------------------------------------------------
// fp32 -> bf16 bulk conversion (float4 -> ushort4 per thread), same layout
__global__ void cvt_bf16_kernel(const float* __restrict__ in,
                                ushort* __restrict__ out, int n4) {
    int i = blockIdx.x * blockDim.x + threadIdx.x;
    if (i >= n4) return;
    float4 v = *(const float4*)&in[(size_t)i * 4];
    ushort4 w;
    w.x = f2bf(v.x); w.y = f2bf(v.y); w.z = f2bf(v.z); w.w = f2bf(v.w);
    *(ushort4*)&out[(size_t)i * 4] = w;
}

// ===========================================================================
// FULL TIER: bf16 pre-staged MFMA candidate pass, 2-deep pipelined.
// Flattened 64-step loop (r18/r20-proven: VGPR 64, occupancy ~40%).
// LDS rows = 36 ushorts (72B, stride 18 dwords) + 8B-granule XOR swizzle
// g' = g ^ ((row>>4)&7): read-side key is compile-time per fragment instr
// (read banks unchanged, already minimal); commitA's 8-way write conflict
// spreads to ~2-way. Layout-only — stored bits identical.
// ===========================================================================
__global__ __launch_bounds__(512) void mfma_pass16(
    const ushort* __restrict__ src16, const ushort* __restrict__ cb16q,
    const float* __restrict__ cn,   // pre-offset by q*VQ
    float* __restrict__ idx_out, int* __restrict__ nflag,
    int2* __restrict__ pair_list, int* __restrict__ full_list, int q)
{
    __shared__ ushort As[2][128][36];   // 18 KiB
    __shared__ ushort Bs[2][256][36];   // 36 KiB
    __shared__ float  cn_l[256];
    __shared__ float  RB1[128][4], RB2[128][4], RB3[128][4];
    __shared__ int    RI1[128][4], RI2[128][4];

    const int tid = threadIdx.x;
    const int n0  = blockIdx.x * 128;
    const int b   = n0 / TQ;
    const int t0  = n0 % TQ;

    const int wv = tid >> 6, l = tid & 63;
    const int wrow = (wv >> 2) * 64;
    const int wcol = (wv & 3) * 64;
    const int cw   = wv & 3;
    const int lr = l & 15, lk = l >> 4;

    // staging decomposition (all 512 threads stage both A and B)
    const int a_tg  = tid & 31;           // 4 consecutive t's
    const int a_kg2 = (tid >> 5) & 15;    // 2 consecutive k's
    const int b_code = tid >> 1;          // one code per thread pair
    const int b_half = tid & 1;           // 32B half of the 64B k-row

    ushort4 aU[2];    // aU[u] = t0..t3 at k = a_kg2*2+u
    uint4   bU[2];    // 32B = 16 ushorts of code b_code

    auto issueA = [&](int kt) {
        #pragma unroll
        for (int u = 0; u < 2; u++)
            aU[u] = *(const ushort4*)&src16[((size_t)(b * DQ + kt * 32 + a_kg2 * 2 + u)) * TQ + t0 + a_tg * 4];
    };
    // swizzled commit: dword kg2 -> granule (kg2>>1)^s, dword-in-granule kg2&1
    auto commitA = [&](int bf) {
        #pragma unroll
        for (int i = 0; i < 4; i++) {
            const int t = a_tg * 4 + i;
            const int s = (t >> 4) & 7;
            const int col = (((a_kg2 >> 1) ^ s) << 2) + ((a_kg2 & 1) << 1);
            ushort2 w;
            w.x = ((const ushort*)&aU[0])[i];
            w.y = ((const ushort*)&aU[1])[i];
            *(ushort2*)&As[bf][t][col] = w;
        }
    };
    auto issueB = [&](int vt, int kt) {
        const ushort* bp = cb16q + (size_t)(vt * 256 + b_code) * DQ + kt * 32 + b_half * 16;
        bU[0] = *(const uint4*)&bp[0];
        bU[1] = *(const uint4*)&bp[8];
    };
    auto commitB = [&](int bf) {
        const int s = (b_code >> 4) & 7;
        ushort* row = &Bs[bf][b_code][0];
        #pragma unroll
        for (int gg = 0; gg < 4; gg++) {
            const int g = b_half * 4 + gg;          // source granule (8B)
            const int col = ((g ^ s) << 2);
            *(uint2*)&row[col] = *((const uint2*)&bU[0] + gg);
        }
    };

    if (tid < 128) {
        #pragma unroll
        for (int j = 0; j < 4; j++) {
            RB1[tid][j] = INFINITY; RB2[tid][j] = INFINITY; RB3[tid][j] = INFINITY;
            RI1[tid][j] = 0; RI2[tid][j] = 0;
        }
    }

    // prologue: step0 staged into buf0; step1 loads in flight
    issueA(0); issueB(0, 0);
    commitA(0); commitB(0);
    issueA(1); issueB(0, 1);

    f32x4 acc[4][4];
    #pragma unroll
    for (int rt = 0; rt < 4; rt++)
        #pragma unroll
        for (int ct = 0; ct < 4; ct++) {
            f32x4 z = {0.f, 0.f, 0.f, 0.f};
            acc[rt][ct] = z;
        }

    for (int s = 0; s < 64; s++) {
        __syncthreads();                                 // buf[s&1] ready
        if ((s & 15) == 0 && tid < 256) cn_l[tid] = cn[(s >> 4) * 256 + tid];
        if (s < 63) { commitA((s + 1) & 1); commitB((s + 1) & 1); }  // write-late
        if (s < 62) { issueA((s + 2) & 15); issueB((s + 2) >> 4, (s + 2) & 15); }
        const int cur = s & 1;

        FragU fa[4], fb[4];
        #pragma unroll
        for (int rt = 0; rt < 4; rt++) {
            const int t = wrow + rt * 16 + lr;
            const int sw = (t >> 4) & 7;                 // == ((wrow>>4)+rt)&7
            fa[rt].h[0] = *(const ushort4*)&As[cur][t][(((lk * 2)     ^ sw) << 2)];
            fa[rt].h[1] = *(const ushort4*)&As[cur][t][(((lk * 2 + 1) ^ sw) << 2)];
        }
        #pragma unroll
        for (int ct = 0; ct < 4; ct++) {
            const int c = wcol + ct * 16 + lr;
            const int sw = (c >> 4) & 7;                 // == ((wcol>>4)+ct)&7
            fb[ct].h[0] = *(const ushort4*)&Bs[cur][c][(((lk * 2)     ^ sw) << 2)];
            fb[ct].h[1] = *(const ushort4*)&Bs[cur][c][(((lk * 2 + 1) ^ sw) << 2)];
        }
        #pragma unroll
        for (int rt = 0; rt < 4; rt++)
            #pragma unroll
            for (int ct = 0; ct < 4; ct++)
                acc[rt][ct] = __builtin_amdgcn_mfma_f32_16x16x32_bf16(
                    fa[rt].v, fb[ct].v, acc[rt][ct], 0, 0, 0);

        if ((s & 15) == 15) {
            const int vt = s >> 4;
            // fold: per slot, local top-3 of 4 ct-candidates -> butterfly over
            // 16 col-lanes -> lr==0 merges into LDS row state.
            #pragma unroll
            for (int sl = 0; sl < 16; sl++) {
                const int rt = sl >> 2, r = sl & 3;
                float l1 = INFINITY, l2 = INFINITY, l3 = INFINITY;
                int j1 = 0, j2 = 0;
                #pragma unroll
                for (int ct = 0; ct < 4; ct++) {
                    const int c = vt * 256 + wcol + ct * 16 + lr;
                    float est = fmaf(-2.f, acc[rt][ct][r], cn_l[wcol + ct * 16 + lr]);
                    if (est < l1)      { l3 = l2; l2 = l1; j2 = j1; l1 = est; j1 = c; }
                    else if (est < l2) { l3 = l2; l2 = est; j2 = c; }
                    else if (est < l3) { l3 = est; }
                }
                #pragma unroll
                for (int m = 1; m <= 8; m <<= 1) {
                    float ob1 = __shfl_xor(l1, m, 64), ob2 = __shfl_xor(l2, m, 64);
                    float ob3 = __shfl_xor(l3, m, 64);
                    int  oj1 = __shfl_xor(j1, m, 64), oj2 = __shfl_xor(j2, m, 64);
                    bool aw = (l1 < ob1) || (l1 == ob1 && j1 < oj1);
                    float n1, n2, n3; int k1, k2;
                    if (aw) {
                        n1 = l1; k1 = j1;
                        bool a2w = (l2 < ob1) || (l2 == ob1 && j2 < oj1);
                        if (a2w) { n2 = l2; k2 = j2; n3 = fminf(l3, ob1); }
                        else     { n2 = ob1; k2 = oj1; n3 = fminf(l2, ob2); }
                    } else {
                        n1 = ob1; k1 = oj1;
                        bool b2w = (ob2 < l1) || (ob2 == l1 && oj2 < j1);
                        if (b2w) { n2 = ob2; k2 = oj2; n3 = fminf(ob3, l1); }
                        else     { n2 = l1; k2 = j1; n3 = fminf(ob2, l2); }
                    }
                    l1 = n1; j1 = k1; l2 = n2; j2 = k2; l3 = n3;
                }
                if (lr == 0) {
                    const int row = wrow + rt * 16 + lk * 4 + r;
                    float g1 = RB1[row][cw], g2 = RB2[row][cw], g3 = RB3[row][cw];
                    int   h1 = RI1[row][cw], h2 = RI2[row][cw];
                    bool aw = (g1 < l1) || (g1 == l1 && h1 < j1);
                    float n1, n2, n3; int k1, k2;
                    if (aw) {
                        n1 = g1; k1 = h1;
                        bool a2w = (g2 < l1) || (g2 == l1 && h2 < j1);
                        if (a2w) { n2 = g2; k2 = h2; n3 = fminf(g3, l1); }
                        else     { n2 = l1; k2 = j1; n3 = fminf(g2, l2); }
                    } else {
                        n1 = l1; k1 = j1;
                        bool b2w = (l2 < g1) || (l2 == g1 && j2 < h1);
                        if (b2w) { n2 = l2; k2 = j2; n3 = fminf(l3, g1); }
                        else     { n2 = g1; k2 = h1; n3 = fminf(l2, g2); }
                    }
                    RB1[row][cw] = n1; RI1[row][cw] = k1;
                    RB2[row][cw] = n2; RI2[row][cw] = k2;
                    RB3[row][cw] = n3;
                }
            }
            // reset acc for next vt
            #pragma unroll
            for (int rt = 0; rt < 4; rt++)
                #pragma unroll
                for (int ct = 0; ct < 4; ct++) {
                    f32x4 z = {0.f, 0.f, 0.f, 0.f};
                    acc[rt][ct] = z;
                }
        }
    }
    __syncthreads();

    // final 4-colwave merge per row + classification
    if (tid < 128) {
        float b1 = RB1[tid][0], b2v = RB2[tid][0], b3v = RB3[tid][0];
        int   i1 = RI1[tid][0], i2 = RI2[tid][0];
        #pragma unroll
        for (int j = 1; j < 4; j++) {
            float ob1 = RB1[tid][j], ob2 = RB2[tid][j], ob3 = RB3[tid][j];
            int   oi1 = RI1[tid][j], oi2 = RI2[tid][j];
            bool aw = (b1 < ob1) || (b1 == ob1 && i1 < oi1);
            float n1, n2, n3; int k1, k2;
            if (aw) {
                n1 = b1; k1 = i1;
                bool a2w = (b2v < ob1) || (b2v == ob1 && i2 < oi1);
                if (a2w) { n2 = b2v; k2 = i2; n3 = fminf(b3v, ob1); }
                else     { n2 = ob1; k2 = oi1; n3 = fminf(b2v, ob2); }
            } else {
                n1 = ob1; k1 = oi1;
                bool b2w = (ob2 < b1) || (ob2 == b1 && oi2 < i1);
                if (b2w) { n2 = ob2; k2 = oi2; n3 = fminf(ob3, b1); }
                else     { n2 = b1; k2 = i1; n3 = fminf(ob2, b2v); }
            }
            b1 = n1; i1 = k1; b2v = n2; i2 = k2; b3v = n3;
        }
        const int n = n0 + tid;
        idx_out[(size_t)n * QQ + q] = (float)i1;
        if (b2v - b1 < EPS_TIE) {
            if (b3v - b1 < EPS_TIE) {
                int slot = atomicAdd(&nflag[q * 2 + 1], 1);
                full_list[slot] = n;
            } else {
                int slot = atomicAdd(&nflag[q * 2], 1);
                pair_list[slot] = make_int2(n, i2);
            }
        }
    }
}

// ---------------------------------------------------------------------------
// FUSED exact fp32 refinement (one launch per stage):
//   blocks [0,512)    : pair rows — 256-thread staging, proven 32-lane rn,
//                       tid-0 exact ascending-k chains (bitwise identical).
//   blocks [512,1024) : full rows — identical to proven full_refine body.
__global__ __launch_bounds__(256) void refine_pass(
    const float* __restrict__ src, const float* __restrict__ cb_all,
    const float* __restrict__ cn_all, float* __restrict__ idx_out,
    const int* __restrict__ nflag,
    const int2* __restrict__ pair_list, const int* __restrict__ full_list,
    int q)
{
    #pragma clang fp contract(off)
    __shared__ float rL[DQ];
    __shared__ float pL[2][DQ];
    __shared__ float rn_s;
    __shared__ float wb[4];
    __shared__ int   wi[4];

    const int tid = threadIdx.x;
    const float* cb = cb_all + (size_t)q * VQ * DQ;
    const float* cn = cn_all + q * VQ;

    if (blockIdx.x < 512) {
        // ---------------- pair rows ----------------
        const int total = nflag[q * 2];
        for (int g = blockIdx.x; g < total; g += 512) {
            int2 e = pair_list[g];
            const int n = e.x, c1 = e.y;
            const int c0 = (int)idx_out[(size_t)n * QQ + q];
            const int bb = n / TQ, tt = n % TQ;
            const float* rp = src + (size_t)bb * DQ * TQ + tt;
            const float* p0 = cb + (size_t)c0 * DQ;
            const float* p1 = cb + (size_t)c1 * DQ;

            #pragma unroll
            for (int u = 0; u < 2; u++) {
                const int k = tid + u * 256;
                rL[k]    = rp[(size_t)k * TQ];
                pL[0][k] = p0[k];
                pL[1][k] = p1[k];
            }
            __syncthreads();

            if (tid < 32) {   // proven 32-lane pairwise rn recipe
                const int c = tid >> 3, j = tid & 7;
                float acc = 0.f;
                #pragma unroll
                for (int m = 0; m < 16; m++) {
                    float v = rL[c * 128 + m * 8 + j];
                    float a = v * v;
                    acc = acc + a;
                }
                float s = acc + __shfl_xor(acc, 1, 64);
                s = s + __shfl_xor(s, 2, 64);
                s = s + __shfl_xor(s, 4, 64);
                float t = s + __shfl_xor(s, 8, 64);
                t = t + __shfl_xor(t, 16, 64);
                if (tid == 0) rn_s = t;
            }
            __syncthreads();

            if (tid == 0) {   // exact ascending-k fmaf chains
                float M0 = 0.f, M1 = 0.f;
                for (int k = 0; k < DQ; k++) {
                    float rv = rL[k];
                    M0 = fmaf(rv, pL[0][k], M0);
                    M1 = fmaf(rv, pL[1][k], M1);
                }
                float rn  = rn_s;
                float m20 = 2.0f * M0, m21 = 2.0f * M1;
                float t10 = rn - m20,  t11 = rn - m21;
                float d0 = t10 + cn[c0];
                float d1 = t11 + cn[c1];
                int win = (d1 < d0 || (d1 == d0 && c1 < c0)) ? c1 : c0;
                idx_out[(size_t)n * QQ + q] = (float)win;
            }
            __syncthreads();
        }
    } else {
        // ---------------- full rows ----------------
        const int total = nflag[q * 2 + 1];
        for (int g = blockIdx.x - 512; g < total; g += 512) {
            const int n = full_list[g];
            const int bb = n / TQ, tt = n % TQ;
            #pragma unroll
            for (int u = 0; u < 2; u++) {
                int k = tid + u * 256;
                rL[k] = src[((size_t)bb * DQ + k) * TQ + tt];
            }
            __syncthreads();
            if (tid < 32) {
                const int c = tid >> 3, j = tid & 7;
                float acc = 0.f;
                #pragma unroll
                for (int m = 0; m < 16; m++) {
                    float v = rL[c * 128 + m * 8 + j];
                    float a = v * v;
                    acc = acc + a;
                }
                float s = acc + __shfl_xor(acc, 1, 64);
                s = s + __shfl_xor(s, 2, 64);
                s = s + __shfl_xor(s, 4, 64);
                float t = s + __shfl_xor(s, 8, 64);
                t = t + __shfl_xor(t, 16, 64);
                if (tid == 0) rn_s = t;
            }
            __syncthreads();
            const float rn = rn_s;
            float acc4[4] = {0.f, 0.f, 0.f, 0.f};
            for (int k4 = 0; k4 < 128; k4++) {
                const float4 rv = *(const float4*)&rL[k4 * 4];
                #pragma unroll
                for (int j = 0; j < 4; j++) {
                    const float4 cv = *(const float4*)&cb[(size_t)(tid + 256 * j) * DQ + k4 * 4];
                    acc4[j] = fmaf(rv.x, cv.x, acc4[j]);
                    acc4[j] = fmaf(rv.y, cv.y, acc4[j]);
                    acc4[j] = fmaf(rv.z, cv.z, acc4[j]);
                    acc4[j] = fmaf(rv.w, cv.w, acc4[j]);
                }
            }
            float bv = INFINITY; int bi = 0x7FFFFFFF;
            #pragma unroll
            for (int j = 0; j < 4; j++) {
                const int c = tid + 256 * j;
                float m2 = 2.0f * acc4[j];
                float t1 = rn - m2;
                float d  = t1 + cn[c];
                if (d < bv || (d == bv && c < bi)) { bv = d; bi = c; }
            }
            #pragma unroll
            for (int m = 1; m <= 32; m <<= 1) {
                float ov = __shfl_xor(bv, m, 64);
                int   oi = __shfl_xor(bi, m, 64);
                if (ov < bv || (ov == bv && oi < bi)) { bv = ov; bi = oi; }
            }
            if ((tid & 63) == 0) { wb[tid >> 6] = bv; wi[tid >> 6] = bi; }
            __syncthreads();
            if (tid == 0) {
                #pragma unroll
                for (int w = 1; w < 4; w++)
                    if (wb[w] < bv || (wb[w] == bv && wi[w] < bi)) { bv = wb[w]; bi = wi[w]; }
                idx_out[(size_t)n * QQ + q] = (float)bi;
            }
            __syncthreads();
        }
    }
}

// ---------------------------------------------------------------------------
// Residual update + loss + hist (+ final output at q==Q-1). Proven per-element
// chain, VECTORIZED: thread owns 4 consecutive t's x 8 k's per kc-chunk ->
// float4 src/res/x accesses and ushort4 r16 stores (4x fewer mem instrs).
__global__ __launch_bounds__(256) void phase2_pass(
    const float* __restrict__ x, const float* __restrict__ cb_all,
    const float* __restrict__ src, float* __restrict__ res,
    ushort* __restrict__ r16,      // may be null
    const float* __restrict__ idx_out, int* __restrict__ hist,
    double* __restrict__ loss_acc, int q)
{
    #pragma clang fp contract(off)
    __shared__ float c2[64 * 128];
    __shared__ int   idx_l[64];
    __shared__ double redbuf[4];

    const int tid = threadIdx.x;
    const int n0  = blockIdx.x * 64;
    const int b   = n0 / TQ;
    const int t0  = n0 % TQ;
    const float* cb = cb_all + (size_t)q * VQ * DQ;

    const int tq = tid & 15;        // t-quad: t = tq*4 .. tq*4+3
    const int ch = tid >> 4;        // 16 chunks of 8 k within each kc-128

    if (tid < 64) idx_l[tid] = (int)idx_out[(size_t)(n0 + tid) * QQ + q];
    __syncthreads();
    if (tid < 64) atomicAdd(&hist[q * VQ + idx_l[tid]], 1);

    const bool do16 = (r16 != nullptr) && (q < QQ - 1);
    const bool last = (q == QQ - 1);

    double lsum = 0.0;
    for (int kc = 0; kc < 4; kc++) {
        __syncthreads();
        {   // stage the selected code rows (coalesced 512B per row) — proven
            int kk = tid & 127, r2 = tid >> 7;
            #pragma unroll
            for (int p = 0; p < 32; p++) {
                int rw = p * 2 + r2;
                const float* crow = cb + (size_t)idx_l[rw] * DQ + kc * 128;
                c2[rw * 128 + (kk ^ (rw & 31))] = crow[kk];
            }
        }
        __syncthreads();
        #pragma unroll
        for (int u = 0; u < 8; u++) {
            const int kk = ch * 8 + u;
            const int k  = kc * 128 + kk;
            const size_t o = ((size_t)b * DQ + k) * TQ + t0 + tq * 4;
            const float4 r4 = *(const float4*)&src[o];
            float cvv[4], rr4[4] = {r4.x, r4.y, r4.z, r4.w};
            #pragma unroll
            for (int j = 0; j < 4; j++) {
                const int rw = tq * 4 + j;
                cvv[j] = c2[rw * 128 + (kk ^ (rw & 31))];
            }
            float out4[4];
            ushort pk[4];
            #pragma unroll
            for (int j = 0; j < 4; j++) {
                float r_old = rr4[j];
                float cv = cvv[j];
                float e  = r_old - cv;           // loss term (exact ref chain)
                lsum += (double)e * (double)e;
                float tt = cv - r_old;
                float qs = r_old + tt;           // quant_st, fp32 reference chain
                float rn2 = r_old - qs;          // updated residual
                out4[j] = rn2;
                pk[j] = f2bf(rn2);
            }
            if (!last) {
                *(float4*)&res[o] = *(const float4*)out4;
                if (do16) {
                    ushort4 w4 = {pk[0], pk[1], pk[2], pk[3]};
                    *(ushort4*)&r16[o] = w4;
                }
            } else {
                const float4 x4 = *(const float4*)&x[o];
                float f4[4] = {x4.x - out4[0], x4.y - out4[1],
                               x4.z - out4[2], x4.w - out4[3]};
                *(float4*)&res[o] = *(const float4*)f4;   // quantized_out
            }
        }
    }
    #pragma unroll
    for (int m = 32; m >= 1; m >>= 1) lsum += __shfl_xor(lsum, m, 64);
    if ((tid & 63) == 0) redbuf[tid >> 6] = lsum;
    __syncthreads();
    if (tid == 0)
        atomicAdd(loss_acc + q, redbuf[0] + redbuf[1] + redbuf[2] + redbuf[3]);
}

// ===========================================================================
// FALLBACK: round-6 proven all-fp32 stage kernel (bit-exact)
// ===========================================================================
__global__ __launch_bounds__(256) void vq32_fallback(
    const float* __restrict__ x, const float* __restrict__ cb_all,
    const float* __restrict__ cn_all,
    float* __restrict__ res, float* __restrict__ idx_out,
    int* __restrict__ hist, double* __restrict__ loss_acc, int q)
{
    #pragma clang fp contract(off)
    __shared__ float As[2][32][64];
    __shared__ float Bs[2][32][128];
    __shared__ int   idx_l[64];
    __shared__ float PL[64][4];
    __shared__ float rn_l[64];
    __shared__ double redbuf[4];

    const int tid = threadIdx.x;
    const int n0  = blockIdx.x * 64;
    const int b   = n0 / TQ;
    const int t0  = n0 % TQ;
    const float* cb  = cb_all + (size_t)q * VQ * DQ;
    const float* cn  = cn_all + q * VQ;
    const float* src = (q == 0) ? x : res;

    const int rr  = tid & 63;
    const int kkb = tid >> 6;
    const int kks = tid & 31;
    const int vbs = tid >> 5;
    const int ty  = tid >> 5;
    const int tx  = tid & 31;

    float aR[8], bR[16];

    auto loadA = [&](int kt) {
        const float* sp = src + ((size_t)b * DQ + kt * 32) * TQ + t0 + rr;
        #pragma unroll
        for (int u = 0; u < 8; u++) aR[u] = sp[(size_t)(kkb * 8 + u) * TQ];
    };
    auto loadB = [&](int vt, int kt) {
        const float* bp = cb + (size_t)(vt * 128 + vbs * 16) * DQ + kt * 32 + kks;
        #pragma unroll
        for (int w = 0; w < 16; w++) bR[w] = bp[(size_t)w * DQ];
    };
    auto writeA = [&](int bf) {
        #pragma unroll
        for (int u = 0; u < 8; u++) As[bf][kkb * 8 + u][rr] = aR[u];
    };
    auto writeB = [&](int bf) {
        #pragma unroll
        for (int w = 0; w < 16; w++) Bs[bf][kks][bswz(kks, vbs * 16 + w)] = bR[w];
    };

    float racc[8];
    #pragma unroll
    for (int j = 0; j < 8; j++) racc[j] = 0.f;

    float best[8]; int bidx[8];
    #pragma unroll
    for (int i = 0; i < 8; i++) { best[i] = INFINITY; bidx[i] = 0; }

    loadA(0); loadB(0, 0);
    writeA(0); writeB(0);

    for (int vt = 0; vt < 8; vt++) {
        float acc[8][4];
        #pragma unroll
        for (int i = 0; i < 8; i++)
            #pragma unroll
            for (int j = 0; j < 4; j++) acc[i][j] = 0.f;

        int cur = 0;
        for (int kt = 0; kt < 16; kt++) {
            if (kt < 15) { loadA(kt + 1); loadB(vt, kt + 1); }
            __syncthreads();
            for (int kk = 0; kk < 32; kk++) {
                const float4 a0 = *(const float4*)&As[cur][kk][ty * 8];
                const float4 a1 = *(const float4*)&As[cur][kk][ty * 8 + 4];
                const float4 b0 = *(const float4*)&Bs[cur][kk][bswz(kk, tx * 4)];
                const float av[8] = {a0.x,a0.y,a0.z,a0.w,a1.x,a1.y,a1.z,a1.w};
                const float bv[4] = {b0.x,b0.y,b0.z,b0.w};
                #pragma unroll
                for (int i = 0; i < 8; i++)
                    #pragma unroll
                    for (int j = 0; j < 4; j++)
                        acc[i][j] = fmaf(av[i], bv[j], acc[i][j]);
            }
            if (vt == 0 && (kt >> 2) == kkb) {
                #pragma unroll
                for (int mm = 0; mm < 4; mm++)
                    #pragma unroll
                    for (int j2 = 0; j2 < 8; j2++) {
                        float v = As[cur][mm * 8 + j2][rr];
                        float a2 = v * v;
                        racc[j2] = racc[j2] + a2;
                    }
            }
            if (kt < 15) { writeA(cur ^ 1); writeB(cur ^ 1); }
            cur ^= 1;
        }

        if (vt == 0) {
            float s01 = racc[0] + racc[1], s23 = racc[2] + racc[3];
            float s45 = racc[4] + racc[5], s67 = racc[6] + racc[7];
            PL[rr][kkb] = (s01 + s23) + (s45 + s67);
            __syncthreads();
            if (tid < 64) {
                float a01 = PL[tid][0] + PL[tid][1];
                float a23 = PL[tid][2] + PL[tid][3];
                rn_l[tid] = a01 + a23;
            }
            __syncthreads();
        }

        if (vt < 7) { loadA(0); loadB(vt + 1, 0); }

        #pragma unroll
        for (int j = 0; j < 4; j++) {
            const int v = vt * 128 + tx * 4 + j;
            const float cnv = cn[v];
            #pragma unroll
            for (int i = 0; i < 8; i++) {
                float m2 = 2.0f * acc[i][j];
                float t1 = rn_l[ty * 8 + i] - m2;
                float d  = t1 + cnv;
                if (d < best[i]) { best[i] = d; bidx[i] = v; }
            }
        }

        if (vt < 7) { writeA(0); writeB(0); }
    }

    #pragma unroll
    for (int i = 0; i < 8; i++) {
        float v = best[i]; int ix = bidx[i];
        #pragma unroll
        for (int m = 16; m >= 1; m >>= 1) {
            float ov = __shfl_xor(v, m, 64);
            int   oi = __shfl_xor(ix, m, 64);
            if (ov < v || (ov == v && oi < ix)) { v = ov; ix = oi; }
        }
        if (tx == 0) idx_l[ty * 8 + i] = ix;
    }
    __syncthreads();

    if (tid < 64) {
        int ix = idx_l[tid];
        idx_out[(size_t)(n0 + tid) * QQ + q] = (float)ix;
        atomicAdd(&hist[q * VQ + ix], 1);
    }

    float* c2 = &Bs[0][0][0];
    double lsum = 0.0;
    for (int kc = 0; kc < 4; kc++) {
        __syncthreads();
        {
            int kk = tid & 127, r2 = tid >> 7;
            #pragma unroll
            for (int p = 0; p < 32; p++) {
                int rw = p * 2 + r2;
                const float* crow = cb + (size_t)idx_l[rw] * DQ + kc * 128;
                c2[rw * 128 + (kk ^ (rw & 31))] = crow[kk];
            }
        }
        __syncthreads();
        {
            int kb = tid >> 6;
            #pragma unroll
            for (int w = 0; w < 32; w++) {
                int kk = kb * 32 + w;
                int k  = kc * 128 + kk;
                size_t o = ((size_t)b * DQ + k) * TQ + t0 + rr;
                float cv = c2[rr * 128 + (kk ^ (rr & 31))];
                float r_old = src[o];
                float e  = r_old - cv;
                lsum += (double)e * (double)e;
                float tt = cv - r_old;
                float qs = r_old + tt;
                float rn2 = r_old - qs;
                if (q < QQ - 1) res[o] = rn2;
                else            res[o] = x[o] - rn2;
            }
        }
    }
    #pragma unroll
    for (int m = 32; m >= 1; m >>= 1) lsum += __shfl_xor(lsum, m, 64);
    if ((tid & 63) == 0) redbuf[tid >> 6] = lsum;
    __syncthreads();
    if (tid == 0)
        atomicAdd(loss_acc + q, redbuf[0] + redbuf[1] + redbuf[2] + redbuf[3]);
}

// ---------------------------------------------------------------------------
// Scalars: usage%, loss, perplexity averaged over Q (proven).
__global__ void finalize_kernel(const int* __restrict__ hist,
                                const double* __restrict__ loss_acc,
                                float* __restrict__ outs) {
    int lane = threadIdx.x;  // blockDim = 64
    float usage_sum = 0.f, perp_sum = 0.f;
    for (int q = 0; q < QQ; q++) {
        int nz = 0; float ent = 0.f;
        for (int v = lane; v < VQ; v += 64) {
            int c = hist[q * VQ + v];
            if (c > 0) {
                nz++;
                float p = (float)c / (float)NQ;
                ent += p * logf(p);
            }
        }
        #pragma unroll
        for (int m = 32; m >= 1; m >>= 1) {
            nz  += __shfl_xor(nz, m, 64);
            ent += __shfl_xor(ent, m, 64);
        }
        usage_sum += (float)nz / (float)VQ * 100.f;
        perp_sum  += expf(-ent);
    }
    if (lane == 0) {
        outs[0] = usage_sum / QQ;
        double ls = 0.0;
        for (int q = 0; q < QQ; q++)
            ls += loss_acc[q] * 1.25 / (double)NDQ;
        outs[1] = (float)(ls / QQ);
        outs[2] = perp_sum / QQ;
    }
}

// ---------------------------------------------------------------------------
extern "C" void kernel_launch(void* const* d_in, const int* in_sizes, int n_in,
                              void* d_out, int out_size, void* d_ws, size_t ws_size,
                              hipStream_t stream) {
    const float* x  = (const float*)d_in[0];
    const float* cb = (const float*)d_in[1];

    float* res     = (float*)d_out;          // [0, ND): residual -> quantized_out
    float* scal    = res + NDQ;              // usage, loss, perp
    float* idx_out = scal + 3;               // (B,T,Q) indices as float

    // ws layout: hist | loss | nflag(16) | cn32 | pair_list | full_list [| cb16 | r16]
    const size_t sz_core = (size_t)QQ * VQ * 4 + QQ * 8 + 16 * 4 + (size_t)QQ * VQ * 4
                         + (size_t)NQ * 8 + (size_t)NQ * 4;
    const size_t sz_cb16 = (size_t)QQ * VQ * DQ * 2;
    const size_t sz_r16  = NDQ * 2;
    const size_t need_full = sz_core + sz_cb16 + sz_r16;

    if (ws_size >= need_full) {
        int*    hist      = (int*)d_ws;
        double* loss_acc  = (double*)(hist + QQ * VQ);
        int*    nflag     = (int*)(loss_acc + QQ);
        float*  cn32      = (float*)(nflag + 16);
        int2*   pair_list = (int2*)(cn32 + QQ * VQ);
        int*    full_list = (int*)(pair_list + NQ);
        ushort* cb16      = (ushort*)(full_list + NQ);
        ushort* r16       = cb16 + (size_t)QQ * VQ * DQ;

        hipMemsetAsync(d_ws, 0,
                       QQ * VQ * sizeof(int) + QQ * sizeof(double) + 16 * sizeof(int),
                       stream);
        cnorm32_kernel<<<(QQ * VQ) / 8, 256, 0, stream>>>(cb, cn32);
        cvt_bf16_kernel<<<(QQ * VQ * DQ / 4 + 255) / 256, 256, 0, stream>>>(
            cb, cb16, QQ * VQ * DQ / 4);
        cvt_bf16_kernel<<<(int)(NDQ / 4 / 256), 256, 0, stream>>>(
            x, r16, (int)(NDQ / 4));

        for (int q = 0; q < QQ; q++) {
            const float* srcq = (q == 0) ? x : res;
            mfma_pass16<<<NQ / 128, 512, 0, stream>>>(
                r16, cb16 + (size_t)q * VQ * DQ, cn32 + q * VQ,
                idx_out, nflag, pair_list, full_list, q);
            refine_pass<<<1024, 256, 0, stream>>>(srcq, cb, cn32, idx_out,
                                                  nflag, pair_list, full_list, q);
            phase2_pass<<<NQ / 64, 256, 0, stream>>>(
                x, cb, srcq, res, r16, idx_out, hist, loss_acc, q);
        }
        finalize_kernel<<<1, 64, 0, stream>>>(hist, loss_acc, scal);
    } else {
        // proven fp32 fallback (round-6 path)
        int*    hist     = (int*)d_ws;
        double* loss_acc = (double*)((char*)d_ws + QQ * VQ * sizeof(int));
        float*  cn32     = (float*)(loss_acc + QQ);

        hipMemsetAsync(d_ws, 0, QQ * VQ * sizeof(int) + QQ * sizeof(double), stream);
        cnorm32_kernel<<<(QQ * VQ) / 8, 256, 0, stream>>>(cb, cn32);
        for (int q = 0; q < QQ; q++)
            vq32_fallback<<<NQ / 64, 256, 0, stream>>>(x, cb, cn32, res, idx_out,
                                                       hist, loss_acc, q);
        finalize_kernel<<<1, 64, 0, stream>>>(hist, loss_acc, scal);
    }
}

// Round 23
// 2641.132 us; speedup vs baseline: 1.2062x; 1.2062x over previous
//
#include <hip/hip_runtime.h>
#include <math.h>

// Problem constants (fixed by the reference)
#define BQ 32
#define DQ 512
#define TQ 2048
#define VQ 1024
#define QQ 6
#define NQ (BQ * TQ)                 // 65536 rows
#define NDQ ((size_t)NQ * DQ)        // 33,554,432 elements

#define EPS_TIE 1.5f    // bf16-est near-tie margin (>>8 sigma of bf16 GEMM noise)

typedef __attribute__((ext_vector_type(8))) short short8;   // 8 bf16 (4 VGPR)
typedef __attribute__((ext_vector_type(4))) float f32x4;    // MFMA acc

union FragU { ushort4 h[2]; short8 v; };

// fp32 -> bf16 RNE (bit trick; exactness of this rounding is NOT relied upon)
__device__ __forceinline__ ushort f2bf(float f) {
    unsigned u = __float_as_uint(f);
    return (ushort)((u + 0x7FFFu + ((u >> 16) & 1u)) >> 16);
}

// B-tile LDS swizzle (layout only; values untouched) — fallback path
__device__ __forceinline__ int bswz(int kk, int vv) {
    return vv ^ ((((kk & 7) ^ ((vv >> 5) & 7))) << 2);
}

// ---------------------------------------------------------------------------
// numpy-pairwise fp32 ||c||^2 (proven bit-exact)
__global__ void cnorm32_kernel(const float* __restrict__ cb, float* __restrict__ cn) {
    #pragma clang fp contract(off)
    int gw = (blockIdx.x * blockDim.x + threadIdx.x) >> 5;
    int l  = threadIdx.x & 31;
    if (gw >= QQ * VQ) return;
    const float* row = cb + (size_t)gw * DQ;
    const int c = l >> 3, j = l & 7;
    float acc = 0.f;
    #pragma unroll
    for (int m = 0; m < 16; m++) {
        float v = row[c * 128 + m * 8 + j];
        float a = v * v;
        acc = acc + a;
    }
    float s = acc + __shfl_xor(acc, 1, 64);
    s = s + __shfl_xor(s, 2, 64);
    s = s + __shfl_xor(s, 4, 64);
    float t = s + __shfl_xor(s, 8, 64);
    t = t + __shfl_xor(t, 16, 64);
    if (l == 0) cn[gw] = t;
}

// ---------------------------------------------------------------------------
// fp32 -> bf16 bulk conversion (float4 -> ushort4 per thread), same layout
__global__ void cvt_bf16_kernel(const float* __restrict__ in,
                                ushort* __restrict__ out, int n4) {
    int i = blockIdx.x * blockDim.x + threadIdx.x;
    if (i >= n4) return;
    float4 v = *(const float4*)&in[(size_t)i * 4];
    ushort4 w;
    w.x = f2bf(v.x); w.y = f2bf(v.y); w.z = f2bf(v.z); w.w = f2bf(v.w);
    *(ushort4*)&out[(size_t)i * 4] = w;
}

// ===========================================================================
// FULL TIER: bf16 pre-staged MFMA candidate pass, 2-deep pipelined.
// Flattened 64-step loop (r18/r20-proven: VGPR 64, occupancy ~40%, 248 us).
// LDS rows = 36 ushorts (72B): stride 18 dwords, gcd(18,32)=2 -> 16-bank
// spread (r13-measured 6.4e6 conflict cycles vs 4.4e7 at 40-ushort rows).
// ===========================================================================
__global__ __launch_bounds__(512) void mfma_pass16(
    const ushort* __restrict__ src16, const ushort* __restrict__ cb16q,
    const float* __restrict__ cn,   // pre-offset by q*VQ
    float* __restrict__ idx_out, int* __restrict__ nflag,
    int2* __restrict__ pair_list, int* __restrict__ full_list, int q)
{
    __shared__ ushort As[2][128][36];   // 18 KiB
    __shared__ ushort Bs[2][256][36];   // 36 KiB
    __shared__ float  cn_l[256];
    __shared__ float  RB1[128][4], RB2[128][4], RB3[128][4];
    __shared__ int    RI1[128][4], RI2[128][4];

    const int tid = threadIdx.x;
    const int n0  = blockIdx.x * 128;
    const int b   = n0 / TQ;
    const int t0  = n0 % TQ;

    const int wv = tid >> 6, l = tid & 63;
    const int wrow = (wv >> 2) * 64;
    const int wcol = (wv & 3) * 64;
    const int cw   = wv & 3;
    const int lr = l & 15, lk = l >> 4;

    // staging decomposition (all 512 threads stage both A and B)
    const int a_tg  = tid & 31;           // 4 consecutive t's
    const int a_kg2 = (tid >> 5) & 15;    // 2 consecutive k's
    const int b_code = tid >> 1;          // one code per thread pair
    const int b_half = tid & 1;           // 32B half of the 64B k-row

    ushort4 aU[2];    // aU[u] = t0..t3 at k = a_kg2*2+u
    uint4   bU[2];    // 32B = 16 ushorts of code b_code

    auto issueA = [&](int kt) {
        #pragma unroll
        for (int u = 0; u < 2; u++)
            aU[u] = *(const ushort4*)&src16[((size_t)(b * DQ + kt * 32 + a_kg2 * 2 + u)) * TQ + t0 + a_tg * 4];
    };
    auto commitA = [&](int bf) {
        #pragma unroll
        for (int i = 0; i < 4; i++) {
            ushort2 w;
            w.x = ((const ushort*)&aU[0])[i];
            w.y = ((const ushort*)&aU[1])[i];
            *(ushort2*)&As[bf][a_tg * 4 + i][a_kg2 * 2] = w;
        }
    };
    auto issueB = [&](int vt, int kt) {
        const ushort* bp = cb16q + (size_t)(vt * 256 + b_code) * DQ + kt * 32 + b_half * 16;
        bU[0] = *(const uint4*)&bp[0];
        bU[1] = *(const uint4*)&bp[8];
    };
    auto commitB = [&](int bf) {
        ushort* row = &Bs[bf][b_code][b_half * 16];
        *(uint2*)&row[0]  = *((const uint2*)&bU[0] + 0);
        *(uint2*)&row[4]  = *((const uint2*)&bU[0] + 1);
        *(uint2*)&row[8]  = *((const uint2*)&bU[1] + 0);
        *(uint2*)&row[12] = *((const uint2*)&bU[1] + 1);
    };

    if (tid < 128) {
        #pragma unroll
        for (int j = 0; j < 4; j++) {
            RB1[tid][j] = INFINITY; RB2[tid][j] = INFINITY; RB3[tid][j] = INFINITY;
            RI1[tid][j] = 0; RI2[tid][j] = 0;
        }
    }

    // prologue: step0 staged into buf0; step1 loads in flight
    issueA(0); issueB(0, 0);
    commitA(0); commitB(0);
    issueA(1); issueB(0, 1);

    f32x4 acc[4][4];
    #pragma unroll
    for (int rt = 0; rt < 4; rt++)
        #pragma unroll
        for (int ct = 0; ct < 4; ct++) {
            f32x4 z = {0.f, 0.f, 0.f, 0.f};
            acc[rt][ct] = z;
        }

    for (int s = 0; s < 64; s++) {
        __syncthreads();                                 // buf[s&1] ready
        if ((s & 15) == 0 && tid < 256) cn_l[tid] = cn[(s >> 4) * 256 + tid];
        if (s < 63) { commitA((s + 1) & 1); commitB((s + 1) & 1); }  // write-late
        if (s < 62) { issueA((s + 2) & 15); issueB((s + 2) >> 4, (s + 2) & 15); }
        const int cur = s & 1;

        FragU fa[4], fb[4];
        #pragma unroll
        for (int rt = 0; rt < 4; rt++) {
            const int t = wrow + rt * 16 + lr;
            fa[rt].h[0] = *(const ushort4*)&As[cur][t][lk * 8];
            fa[rt].h[1] = *(const ushort4*)&As[cur][t][lk * 8 + 4];
        }
        #pragma unroll
        for (int ct = 0; ct < 4; ct++) {
            const int c = wcol + ct * 16 + lr;
            fb[ct].h[0] = *(const ushort4*)&Bs[cur][c][lk * 8];
            fb[ct].h[1] = *(const ushort4*)&Bs[cur][c][lk * 8 + 4];
        }
        #pragma unroll
        for (int rt = 0; rt < 4; rt++)
            #pragma unroll
            for (int ct = 0; ct < 4; ct++)
                acc[rt][ct] = __builtin_amdgcn_mfma_f32_16x16x32_bf16(
                    fa[rt].v, fb[ct].v, acc[rt][ct], 0, 0, 0);

        if ((s & 15) == 15) {
            const int vt = s >> 4;
            // fold: per slot, local top-3 of 4 ct-candidates -> butterfly over
            // 16 col-lanes -> lr==0 merges into LDS row state.
            #pragma unroll
            for (int sl = 0; sl < 16; sl++) {
                const int rt = sl >> 2, r = sl & 3;
                float l1 = INFINITY, l2 = INFINITY, l3 = INFINITY;
                int j1 = 0, j2 = 0;
                #pragma unroll
                for (int ct = 0; ct < 4; ct++) {
                    const int c = vt * 256 + wcol + ct * 16 + lr;
                    float est = fmaf(-2.f, acc[rt][ct][r], cn_l[wcol + ct * 16 + lr]);
                    if (est < l1)      { l3 = l2; l2 = l1; j2 = j1; l1 = est; j1 = c; }
                    else if (est < l2) { l3 = l2; l2 = est; j2 = c; }
                    else if (est < l3) { l3 = est; }
                }
                #pragma unroll
                for (int m = 1; m <= 8; m <<= 1) {
                    float ob1 = __shfl_xor(l1, m, 64), ob2 = __shfl_xor(l2, m, 64);
                    float ob3 = __shfl_xor(l3, m, 64);
                    int  oj1 = __shfl_xor(j1, m, 64), oj2 = __shfl_xor(j2, m, 64);
                    bool aw = (l1 < ob1) || (l1 == ob1 && j1 < oj1);
                    float n1, n2, n3; int k1, k2;
                    if (aw) {
                        n1 = l1; k1 = j1;
                        bool a2w = (l2 < ob1) || (l2 == ob1 && j2 < oj1);
                        if (a2w) { n2 = l2; k2 = j2; n3 = fminf(l3, ob1); }
                        else     { n2 = ob1; k2 = oj1; n3 = fminf(l2, ob2); }
                    } else {
                        n1 = ob1; k1 = oj1;
                        bool b2w = (ob2 < l1) || (ob2 == l1 && oj2 < j1);
                        if (b2w) { n2 = ob2; k2 = oj2; n3 = fminf(ob3, l1); }
                        else     { n2 = l1; k2 = j1; n3 = fminf(ob2, l2); }
                    }
                    l1 = n1; j1 = k1; l2 = n2; j2 = k2; l3 = n3;
                }
                if (lr == 0) {
                    const int row = wrow + rt * 16 + lk * 4 + r;
                    float g1 = RB1[row][cw], g2 = RB2[row][cw], g3 = RB3[row][cw];
                    int   h1 = RI1[row][cw], h2 = RI2[row][cw];
                    bool aw = (g1 < l1) || (g1 == l1 && h1 < j1);
                    float n1, n2, n3; int k1, k2;
                    if (aw) {
                        n1 = g1; k1 = h1;
                        bool a2w = (g2 < l1) || (g2 == l1 && h2 < j1);
                        if (a2w) { n2 = g2; k2 = h2; n3 = fminf(g3, l1); }
                        else     { n2 = l1; k2 = j1; n3 = fminf(g2, l2); }
                    } else {
                        n1 = l1; k1 = j1;
                        bool b2w = (l2 < g1) || (l2 == g1 && j2 < h1);
                        if (b2w) { n2 = l2; k2 = j2; n3 = fminf(l3, g1); }
                        else     { n2 = g1; k2 = h1; n3 = fminf(l2, g2); }
                    }
                    RB1[row][cw] = n1; RI1[row][cw] = k1;
                    RB2[row][cw] = n2; RI2[row][cw] = k2;
                    RB3[row][cw] = n3;
                }
            }
            // reset acc for next vt
            #pragma unroll
            for (int rt = 0; rt < 4; rt++)
                #pragma unroll
                for (int ct = 0; ct < 4; ct++) {
                    f32x4 z = {0.f, 0.f, 0.f, 0.f};
                    acc[rt][ct] = z;
                }
        }
    }
    __syncthreads();

    // final 4-colwave merge per row + classification
    if (tid < 128) {
        float b1 = RB1[tid][0], b2v = RB2[tid][0], b3v = RB3[tid][0];
        int   i1 = RI1[tid][0], i2 = RI2[tid][0];
        #pragma unroll
        for (int j = 1; j < 4; j++) {
            float ob1 = RB1[tid][j], ob2 = RB2[tid][j], ob3 = RB3[tid][j];
            int   oi1 = RI1[tid][j], oi2 = RI2[tid][j];
            bool aw = (b1 < ob1) || (b1 == ob1 && i1 < oi1);
            float n1, n2, n3; int k1, k2;
            if (aw) {
                n1 = b1; k1 = i1;
                bool a2w = (b2v < ob1) || (b2v == ob1 && i2 < oi1);
                if (a2w) { n2 = b2v; k2 = i2; n3 = fminf(b3v, ob1); }
                else     { n2 = ob1; k2 = oi1; n3 = fminf(b2v, ob2); }
            } else {
                n1 = ob1; k1 = oi1;
                bool b2w = (ob2 < b1) || (ob2 == b1 && oi2 < i1);
                if (b2w) { n2 = ob2; k2 = oi2; n3 = fminf(ob3, b1); }
                else     { n2 = b1; k2 = i1; n3 = fminf(ob2, b2v); }
            }
            b1 = n1; i1 = k1; b2v = n2; i2 = k2; b3v = n3;
        }
        const int n = n0 + tid;
        idx_out[(size_t)n * QQ + q] = (float)i1;
        if (b2v - b1 < EPS_TIE) {
            if (b3v - b1 < EPS_TIE) {
                int slot = atomicAdd(&nflag[q * 2 + 1], 1);
                full_list[slot] = n;
            } else {
                int slot = atomicAdd(&nflag[q * 2], 1);
                pair_list[slot] = make_int2(n, i2);
            }
        }
    }
}

// ---------------------------------------------------------------------------
// FUSED exact fp32 refinement (one launch per stage):
//   blocks [0,512)    : pair rows — 256-thread staging, proven 32-lane rn,
//                       tid-0 exact ascending-k chains (bitwise identical).
//   blocks [512,1024) : full rows — identical to proven full_refine body.
__global__ __launch_bounds__(256) void refine_pass(
    const float* __restrict__ src, const float* __restrict__ cb_all,
    const float* __restrict__ cn_all, float* __restrict__ idx_out,
    const int* __restrict__ nflag,
    const int2* __restrict__ pair_list, const int* __restrict__ full_list,
    int q)
{
    #pragma clang fp contract(off)
    __shared__ float rL[DQ];
    __shared__ float pL[2][DQ];
    __shared__ float rn_s;
    __shared__ float wb[4];
    __shared__ int   wi[4];

    const int tid = threadIdx.x;
    const float* cb = cb_all + (size_t)q * VQ * DQ;
    const float* cn = cn_all + q * VQ;

    if (blockIdx.x < 512) {
        // ---------------- pair rows ----------------
        const int total = nflag[q * 2];
        for (int g = blockIdx.x; g < total; g += 512) {
            int2 e = pair_list[g];
            const int n = e.x, c1 = e.y;
            const int c0 = (int)idx_out[(size_t)n * QQ + q];
            const int bb = n / TQ, tt = n % TQ;
            const float* rp = src + (size_t)bb * DQ * TQ + tt;
            const float* p0 = cb + (size_t)c0 * DQ;
            const float* p1 = cb + (size_t)c1 * DQ;

            #pragma unroll
            for (int u = 0; u < 2; u++) {
                const int k = tid + u * 256;
                rL[k]    = rp[(size_t)k * TQ];
                pL[0][k] = p0[k];
                pL[1][k] = p1[k];
            }
            __syncthreads();

            if (tid < 32) {   // proven 32-lane pairwise rn recipe
                const int c = tid >> 3, j = tid & 7;
                float acc = 0.f;
                #pragma unroll
                for (int m = 0; m < 16; m++) {
                    float v = rL[c * 128 + m * 8 + j];
                    float a = v * v;
                    acc = acc + a;
                }
                float s = acc + __shfl_xor(acc, 1, 64);
                s = s + __shfl_xor(s, 2, 64);
                s = s + __shfl_xor(s, 4, 64);
                float t = s + __shfl_xor(s, 8, 64);
                t = t + __shfl_xor(t, 16, 64);
                if (tid == 0) rn_s = t;
            }
            __syncthreads();

            if (tid == 0) {   // exact ascending-k fmaf chains
                float M0 = 0.f, M1 = 0.f;
                for (int k = 0; k < DQ; k++) {
                    float rv = rL[k];
                    M0 = fmaf(rv, pL[0][k], M0);
                    M1 = fmaf(rv, pL[1][k], M1);
                }
                float rn  = rn_s;
                float m20 = 2.0f * M0, m21 = 2.0f * M1;
                float t10 = rn - m20,  t11 = rn - m21;
                float d0 = t10 + cn[c0];
                float d1 = t11 + cn[c1];
                int win = (d1 < d0 || (d1 == d0 && c1 < c0)) ? c1 : c0;
                idx_out[(size_t)n * QQ + q] = (float)win;
            }
            __syncthreads();
        }
    } else {
        // ---------------- full rows ----------------
        const int total = nflag[q * 2 + 1];
        for (int g = blockIdx.x - 512; g < total; g += 512) {
            const int n = full_list[g];
            const int bb = n / TQ, tt = n % TQ;
            #pragma unroll
            for (int u = 0; u < 2; u++) {
                int k = tid + u * 256;
                rL[k] = src[((size_t)bb * DQ + k) * TQ + tt];
            }
            __syncthreads();
            if (tid < 32) {
                const int c = tid >> 3, j = tid & 7;
                float acc = 0.f;
                #pragma unroll
                for (int m = 0; m < 16; m++) {
                    float v = rL[c * 128 + m * 8 + j];
                    float a = v * v;
                    acc = acc + a;
                }
                float s = acc + __shfl_xor(acc, 1, 64);
                s = s + __shfl_xor(s, 2, 64);
                s = s + __shfl_xor(s, 4, 64);
                float t = s + __shfl_xor(s, 8, 64);
                t = t + __shfl_xor(t, 16, 64);
                if (tid == 0) rn_s = t;
            }
            __syncthreads();
            const float rn = rn_s;
            float acc4[4] = {0.f, 0.f, 0.f, 0.f};
            for (int k4 = 0; k4 < 128; k4++) {
                const float4 rv = *(const float4*)&rL[k4 * 4];
                #pragma unroll
                for (int j = 0; j < 4; j++) {
                    const float4 cv = *(const float4*)&cb[(size_t)(tid + 256 * j) * DQ + k4 * 4];
                    acc4[j] = fmaf(rv.x, cv.x, acc4[j]);
                    acc4[j] = fmaf(rv.y, cv.y, acc4[j]);
                    acc4[j] = fmaf(rv.z, cv.z, acc4[j]);
                    acc4[j] = fmaf(rv.w, cv.w, acc4[j]);
                }
            }
            float bv = INFINITY; int bi = 0x7FFFFFFF;
            #pragma unroll
            for (int j = 0; j < 4; j++) {
                const int c = tid + 256 * j;
                float m2 = 2.0f * acc4[j];
                float t1 = rn - m2;
                float d  = t1 + cn[c];
                if (d < bv || (d == bv && c < bi)) { bv = d; bi = c; }
            }
            #pragma unroll
            for (int m = 1; m <= 32; m <<= 1) {
                float ov = __shfl_xor(bv, m, 64);
                int   oi = __shfl_xor(bi, m, 64);
                if (ov < bv || (ov == bv && oi < bi)) { bv = ov; bi = oi; }
            }
            if ((tid & 63) == 0) { wb[tid >> 6] = bv; wi[tid >> 6] = bi; }
            __syncthreads();
            if (tid == 0) {
                #pragma unroll
                for (int w = 1; w < 4; w++)
                    if (wb[w] < bv || (wb[w] == bv && wi[w] < bi)) { bv = wb[w]; bi = wi[w]; }
                idx_out[(size_t)n * QQ + q] = (float)bi;
            }
            __syncthreads();
        }
    }
}

// ---------------------------------------------------------------------------
// Residual update + loss + hist (+ final output at q==Q-1). Proven per-element
// chain, VECTORIZED: thread owns 4 consecutive t's x 8 k's per kc-chunk ->
// float4 src/res/x accesses and ushort4 r16 stores (4x fewer mem instrs).
__global__ __launch_bounds__(256) void phase2_pass(
    const float* __restrict__ x, const float* __restrict__ cb_all,
    const float* __restrict__ src, float* __restrict__ res,
    ushort* __restrict__ r16,      // may be null
    const float* __restrict__ idx_out, int* __restrict__ hist,
    double* __restrict__ loss_acc, int q)
{
    #pragma clang fp contract(off)
    __shared__ float c2[64 * 128];
    __shared__ int   idx_l[64];
    __shared__ double redbuf[4];

    const int tid = threadIdx.x;
    const int n0  = blockIdx.x * 64;
    const int b   = n0 / TQ;
    const int t0  = n0 % TQ;
    const float* cb = cb_all + (size_t)q * VQ * DQ;

    const int tq = tid & 15;        // t-quad: t = tq*4 .. tq*4+3
    const int ch = tid >> 4;        // 16 chunks of 8 k within each kc-128

    if (tid < 64) idx_l[tid] = (int)idx_out[(size_t)(n0 + tid) * QQ + q];
    __syncthreads();
    if (tid < 64) atomicAdd(&hist[q * VQ + idx_l[tid]], 1);

    const bool do16 = (r16 != nullptr) && (q < QQ - 1);
    const bool last = (q == QQ - 1);

    double lsum = 0.0;
    for (int kc = 0; kc < 4; kc++) {
        __syncthreads();
        {   // stage the selected code rows (coalesced 512B per row) — proven
            int kk = tid & 127, r2 = tid >> 7;
            #pragma unroll
            for (int p = 0; p < 32; p++) {
                int rw = p * 2 + r2;
                const float* crow = cb + (size_t)idx_l[rw] * DQ + kc * 128;
                c2[rw * 128 + (kk ^ (rw & 31))] = crow[kk];
            }
        }
        __syncthreads();
        #pragma unroll
        for (int u = 0; u < 8; u++) {
            const int kk = ch * 8 + u;
            const int k  = kc * 128 + kk;
            const size_t o = ((size_t)b * DQ + k) * TQ + t0 + tq * 4;
            const float4 r4 = *(const float4*)&src[o];
            float cvv[4], rr4[4] = {r4.x, r4.y, r4.z, r4.w};
            #pragma unroll
            for (int j = 0; j < 4; j++) {
                const int rw = tq * 4 + j;
                cvv[j] = c2[rw * 128 + (kk ^ (rw & 31))];
            }
            float out4[4];
            ushort pk[4];
            #pragma unroll
            for (int j = 0; j < 4; j++) {
                float r_old = rr4[j];
                float cv = cvv[j];
                float e  = r_old - cv;           // loss term (exact ref chain)
                lsum += (double)e * (double)e;
                float tt = cv - r_old;
                float qs = r_old + tt;           // quant_st, fp32 reference chain
                float rn2 = r_old - qs;          // updated residual
                out4[j] = rn2;
                pk[j] = f2bf(rn2);
            }
            if (!last) {
                *(float4*)&res[o] = *(const float4*)out4;
                if (do16) {
                    ushort4 w4 = {pk[0], pk[1], pk[2], pk[3]};
                    *(ushort4*)&r16[o] = w4;
                }
            } else {
                const float4 x4 = *(const float4*)&x[o];
                float f4[4] = {x4.x - out4[0], x4.y - out4[1],
                               x4.z - out4[2], x4.w - out4[3]};
                *(float4*)&res[o] = *(const float4*)f4;   // quantized_out
            }
        }
    }
    #pragma unroll
    for (int m = 32; m >= 1; m >>= 1) lsum += __shfl_xor(lsum, m, 64);
    if ((tid & 63) == 0) redbuf[tid >> 6] = lsum;
    __syncthreads();
    if (tid == 0)
        atomicAdd(loss_acc + q, redbuf[0] + redbuf[1] + redbuf[2] + redbuf[3]);
}

// ===========================================================================
// FALLBACK: round-6 proven all-fp32 stage kernel (bit-exact)
// ===========================================================================
__global__ __launch_bounds__(256) void vq32_fallback(
    const float* __restrict__ x, const float* __restrict__ cb_all,
    const float* __restrict__ cn_all,
    float* __restrict__ res, float* __restrict__ idx_out,
    int* __restrict__ hist, double* __restrict__ loss_acc, int q)
{
    #pragma clang fp contract(off)
    __shared__ float As[2][32][64];
    __shared__ float Bs[2][32][128];
    __shared__ int   idx_l[64];
    __shared__ float PL[64][4];
    __shared__ float rn_l[64];
    __shared__ double redbuf[4];

    const int tid = threadIdx.x;
    const int n0  = blockIdx.x * 64;
    const int b   = n0 / TQ;
    const int t0  = n0 % TQ;
    const float* cb  = cb_all + (size_t)q * VQ * DQ;
    const float* cn  = cn_all + q * VQ;
    const float* src = (q == 0) ? x : res;

    const int rr  = tid & 63;
    const int kkb = tid >> 6;
    const int kks = tid & 31;
    const int vbs = tid >> 5;
    const int ty  = tid >> 5;
    const int tx  = tid & 31;

    float aR[8], bR[16];

    auto loadA = [&](int kt) {
        const float* sp = src + ((size_t)b * DQ + kt * 32) * TQ + t0 + rr;
        #pragma unroll
        for (int u = 0; u < 8; u++) aR[u] = sp[(size_t)(kkb * 8 + u) * TQ];
    };
    auto loadB = [&](int vt, int kt) {
        const float* bp = cb + (size_t)(vt * 128 + vbs * 16) * DQ + kt * 32 + kks;
        #pragma unroll
        for (int w = 0; w < 16; w++) bR[w] = bp[(size_t)w * DQ];
    };
    auto writeA = [&](int bf) {
        #pragma unroll
        for (int u = 0; u < 8; u++) As[bf][kkb * 8 + u][rr] = aR[u];
    };
    auto writeB = [&](int bf) {
        #pragma unroll
        for (int w = 0; w < 16; w++) Bs[bf][kks][bswz(kks, vbs * 16 + w)] = bR[w];
    };

    float racc[8];
    #pragma unroll
    for (int j = 0; j < 8; j++) racc[j] = 0.f;

    float best[8]; int bidx[8];
    #pragma unroll
    for (int i = 0; i < 8; i++) { best[i] = INFINITY; bidx[i] = 0; }

    loadA(0); loadB(0, 0);
    writeA(0); writeB(0);

    for (int vt = 0; vt < 8; vt++) {
        float acc[8][4];
        #pragma unroll
        for (int i = 0; i < 8; i++)
            #pragma unroll
            for (int j = 0; j < 4; j++) acc[i][j] = 0.f;

        int cur = 0;
        for (int kt = 0; kt < 16; kt++) {
            if (kt < 15) { loadA(kt + 1); loadB(vt, kt + 1); }
            __syncthreads();
            for (int kk = 0; kk < 32; kk++) {
                const float4 a0 = *(const float4*)&As[cur][kk][ty * 8];
                const float4 a1 = *(const float4*)&As[cur][kk][ty * 8 + 4];
                const float4 b0 = *(const float4*)&Bs[cur][kk][bswz(kk, tx * 4)];
                const float av[8] = {a0.x,a0.y,a0.z,a0.w,a1.x,a1.y,a1.z,a1.w};
                const float bv[4] = {b0.x,b0.y,b0.z,b0.w};
                #pragma unroll
                for (int i = 0; i < 8; i++)
                    #pragma unroll
                    for (int j = 0; j < 4; j++)
                        acc[i][j] = fmaf(av[i], bv[j], acc[i][j]);
            }
            if (vt == 0 && (kt >> 2) == kkb) {
                #pragma unroll
                for (int mm = 0; mm < 4; mm++)
                    #pragma unroll
                    for (int j2 = 0; j2 < 8; j2++) {
                        float v = As[cur][mm * 8 + j2][rr];
                        float a2 = v * v;
                        racc[j2] = racc[j2] + a2;
                    }
            }
            if (kt < 15) { writeA(cur ^ 1); writeB(cur ^ 1); }
            cur ^= 1;
        }

        if (vt == 0) {
            float s01 = racc[0] + racc[1], s23 = racc[2] + racc[3];
            float s45 = racc[4] + racc[5], s67 = racc[6] + racc[7];
            PL[rr][kkb] = (s01 + s23) + (s45 + s67);
            __syncthreads();
            if (tid < 64) {
                float a01 = PL[tid][0] + PL[tid][1];
                float a23 = PL[tid][2] + PL[tid][3];
                rn_l[tid] = a01 + a23;
            }
            __syncthreads();
        }

        if (vt < 7) { loadA(0); loadB(vt + 1, 0); }

        #pragma unroll
        for (int j = 0; j < 4; j++) {
            const int v = vt * 128 + tx * 4 + j;
            const float cnv = cn[v];
            #pragma unroll
            for (int i = 0; i < 8; i++) {
                float m2 = 2.0f * acc[i][j];
                float t1 = rn_l[ty * 8 + i] - m2;
                float d  = t1 + cnv;
                if (d < best[i]) { best[i] = d; bidx[i] = v; }
            }
        }

        if (vt < 7) { writeA(0); writeB(0); }
    }

    #pragma unroll
    for (int i = 0; i < 8; i++) {
        float v = best[i]; int ix = bidx[i];
        #pragma unroll
        for (int m = 16; m >= 1; m >>= 1) {
            float ov = __shfl_xor(v, m, 64);
            int   oi = __shfl_xor(ix, m, 64);
            if (ov < v || (ov == v && oi < ix)) { v = ov; ix = oi; }
        }
        if (tx == 0) idx_l[ty * 8 + i] = ix;
    }
    __syncthreads();

    if (tid < 64) {
        int ix = idx_l[tid];
        idx_out[(size_t)(n0 + tid) * QQ + q] = (float)ix;
        atomicAdd(&hist[q * VQ + ix], 1);
    }

    float* c2 = &Bs[0][0][0];
    double lsum = 0.0;
    for (int kc = 0; kc < 4; kc++) {
        __syncthreads();
        {
            int kk = tid & 127, r2 = tid >> 7;
            #pragma unroll
            for (int p = 0; p < 32; p++) {
                int rw = p * 2 + r2;
                const float* crow = cb + (size_t)idx_l[rw] * DQ + kc * 128;
                c2[rw * 128 + (kk ^ (rw & 31))] = crow[kk];
            }
        }
        __syncthreads();
        {
            int kb = tid >> 6;
            #pragma unroll
            for (int w = 0; w < 32; w++) {
                int kk = kb * 32 + w;
                int k  = kc * 128 + kk;
                size_t o = ((size_t)b * DQ + k) * TQ + t0 + rr;
                float cv = c2[rr * 128 + (kk ^ (rr & 31))];
                float r_old = src[o];
                float e  = r_old - cv;
                lsum += (double)e * (double)e;
                float tt = cv - r_old;
                float qs = r_old + tt;
                float rn2 = r_old - qs;
                if (q < QQ - 1) res[o] = rn2;
                else            res[o] = x[o] - rn2;
            }
        }
    }
    #pragma unroll
    for (int m = 32; m >= 1; m >>= 1) lsum += __shfl_xor(lsum, m, 64);
    if ((tid & 63) == 0) redbuf[tid >> 6] = lsum;
    __syncthreads();
    if (tid == 0)
        atomicAdd(loss_acc + q, redbuf[0] + redbuf[1] + redbuf[2] + redbuf[3]);
}

// ---------------------------------------------------------------------------
// Scalars: usage%, loss, perplexity averaged over Q (proven).
__global__ void finalize_kernel(const int* __restrict__ hist,
                                const double* __restrict__ loss_acc,
                                float* __restrict__ outs) {
    int lane = threadIdx.x;  // blockDim = 64
    float usage_sum = 0.f, perp_sum = 0.f;
    for (int q = 0; q < QQ; q++) {
        int nz = 0; float ent = 0.f;
        for (int v = lane; v < VQ; v += 64) {
            int c = hist[q * VQ + v];
            if (c > 0) {
                nz++;
                float p = (float)c / (float)NQ;
                ent += p * logf(p);
            }
        }
        #pragma unroll
        for (int m = 32; m >= 1; m >>= 1) {
            nz  += __shfl_xor(nz, m, 64);
            ent += __shfl_xor(ent, m, 64);
        }
        usage_sum += (float)nz / (float)VQ * 100.f;
        perp_sum  += expf(-ent);
    }
    if (lane == 0) {
        outs[0] = usage_sum / QQ;
        double ls = 0.0;
        for (int q = 0; q < QQ; q++)
            ls += loss_acc[q] * 1.25 / (double)NDQ;
        outs[1] = (float)(ls / QQ);
        outs[2] = perp_sum / QQ;
    }
}

// ---------------------------------------------------------------------------
extern "C" void kernel_launch(void* const* d_in, const int* in_sizes, int n_in,
                              void* d_out, int out_size, void* d_ws, size_t ws_size,
                              hipStream_t stream) {
    const float* x  = (const float*)d_in[0];
    const float* cb = (const float*)d_in[1];

    float* res     = (float*)d_out;          // [0, ND): residual -> quantized_out
    float* scal    = res + NDQ;              // usage, loss, perp
    float* idx_out = scal + 3;               // (B,T,Q) indices as float

    // ws layout: hist | loss | nflag(16) | cn32 | pair_list | full_list [| cb16 | r16]
    const size_t sz_core = (size_t)QQ * VQ * 4 + QQ * 8 + 16 * 4 + (size_t)QQ * VQ * 4
                         + (size_t)NQ * 8 + (size_t)NQ * 4;
    const size_t sz_cb16 = (size_t)QQ * VQ * DQ * 2;
    const size_t sz_r16  = NDQ * 2;
    const size_t need_full = sz_core + sz_cb16 + sz_r16;

    if (ws_size >= need_full) {
        int*    hist      = (int*)d_ws;
        double* loss_acc  = (double*)(hist + QQ * VQ);
        int*    nflag     = (int*)(loss_acc + QQ);
        float*  cn32      = (float*)(nflag + 16);
        int2*   pair_list = (int2*)(cn32 + QQ * VQ);
        int*    full_list = (int*)(pair_list + NQ);
        ushort* cb16      = (ushort*)(full_list + NQ);
        ushort* r16       = cb16 + (size_t)QQ * VQ * DQ;

        hipMemsetAsync(d_ws, 0,
                       QQ * VQ * sizeof(int) + QQ * sizeof(double) + 16 * sizeof(int),
                       stream);
        cnorm32_kernel<<<(QQ * VQ) / 8, 256, 0, stream>>>(cb, cn32);
        cvt_bf16_kernel<<<(QQ * VQ * DQ / 4 + 255) / 256, 256, 0, stream>>>(
            cb, cb16, QQ * VQ * DQ / 4);
        cvt_bf16_kernel<<<(int)(NDQ / 4 / 256), 256, 0, stream>>>(
            x, r16, (int)(NDQ / 4));

        for (int q = 0; q < QQ; q++) {
            const float* srcq = (q == 0) ? x : res;
            mfma_pass16<<<NQ / 128, 512, 0, stream>>>(
                r16, cb16 + (size_t)q * VQ * DQ, cn32 + q * VQ,
                idx_out, nflag, pair_list, full_list, q);
            refine_pass<<<1024, 256, 0, stream>>>(srcq, cb, cn32, idx_out,
                                                  nflag, pair_list, full_list, q);
            phase2_pass<<<NQ / 64, 256, 0, stream>>>(
                x, cb, srcq, res, r16, idx_out, hist, loss_acc, q);
        }
        finalize_kernel<<<1, 64, 0, stream>>>(hist, loss_acc, scal);
    } else {
        // proven fp32 fallback (round-6 path)
        int*    hist     = (int*)d_ws;
        double* loss_acc = (double*)((char*)d_ws + QQ * VQ * sizeof(int));
        float*  cn32     = (float*)(loss_acc + QQ);

        hipMemsetAsync(d_ws, 0, QQ * VQ * sizeof(int) + QQ * sizeof(double), stream);
        cnorm32_kernel<<<(QQ * VQ) / 8, 256, 0, stream>>>(cb, cn32);
        for (int q = 0; q < QQ; q++)
            vq32_fallback<<<NQ / 64, 256, 0, stream>>>(x, cb, cn32, res, idx_out,
                                                       hist, loss_acc, q);
        finalize_kernel<<<1, 64, 0, stream>>>(hist, loss_acc, scal);
    }
}